// Round 15
// baseline (123.777 us; speedup 1.0000x reference)
//
#include <hip/hip_runtime.h>
#include <hip/hip_bf16.h>

typedef __attribute__((ext_vector_type(4))) float f32x4;
typedef __attribute__((ext_vector_type(4))) uint u32x4;
typedef __attribute__((ext_vector_type(8))) short bf16x8;

#define M_TOTAL 32768
#define N_TOTAL 1024
#define K_TOTAL 1024

__device__ __forceinline__ uint pk2(float a, float b) {
  __hip_bfloat162 h = __float22bfloat162_rn(make_float2(a, b));  // v_cvt_pk_bf16_f32
  uint u;
  __builtin_memcpy(&u, &h, 4);
  return u;
}

// Non-draining barrier (fallback kernels only).
#define SOFT_BARRIER() do {                                                   \
    __builtin_amdgcn_sched_barrier(0);                                        \
    asm volatile("s_waitcnt lgkmcnt(0)" ::: "memory");                        \
    __builtin_amdgcn_s_barrier();                                             \
    __builtin_amdgcn_sched_barrier(0);                                        \
  } while (0)

// Per-wave counted waits (gemm10 — NO s_barrier anywhere in that kernel).
#define WAITV8() do {                                                         \
    __builtin_amdgcn_sched_barrier(0);                                        \
    asm volatile("s_waitcnt vmcnt(8)" ::: "memory");                          \
    __builtin_amdgcn_sched_barrier(0);                                        \
  } while (0)
#define WAITV0() do {                                                         \
    __builtin_amdgcn_sched_barrier(0);                                        \
    asm volatile("s_waitcnt vmcnt(0)" ::: "memory");                          \
    __builtin_amdgcn_sched_barrier(0);                                        \
  } while (0)

// ===========================================================================
// Pass 1a: X (32768x1024 f32) -> fragment-major bf16 in wsx (64 MB).
// Frag (fm, kb): 1 KB contiguous; lane l holds
// X[fm*16 + (l&15)][kb*32 + (l>>4)*8 .. +7]. Verified rounds 10-14.
// ===========================================================================
__global__ __launch_bounds__(256) void conv_x(
    const float* __restrict__ X, ushort* __restrict__ wsx)
{
  const int g = blockIdx.x * 256 + (int)threadIdx.x;
  const int wid = g >> 6;   // (fm 0..2047, kb 0..31)
  const int lane = g & 63;
  const int fm = wid >> 5;
  const int kb = wid & 31;
  const float* p = X + (size_t)(fm * 16 + (lane & 15)) * K_TOTAL
                     + kb * 32 + (lane >> 4) * 8;
  f32x4 lo = *(const f32x4*)p;
  f32x4 hi = *(const f32x4*)(p + 4);
  u32x4 v;
  v[0] = pk2(lo[0], lo[1]); v[1] = pk2(lo[2], lo[3]);
  v[2] = pk2(hi[0], hi[1]); v[3] = pk2(hi[2], hi[3]);
  *(u32x4*)(wsx + (size_t)wid * 512 + lane * 8) = v;
}

// ===========================================================================
// Pass 1b (pre-signed): S matrices -> frag-major bf16, BOTH polarities.
// Layout: [sign][si 4][cb 16][kb 8] frags of 1 KB; 1 MB total (L2-resident).
// Positive half identical to the r7-r14-verified layout.
// ===========================================================================
__global__ __launch_bounds__(256) void conv_b2(
    const float* __restrict__ Rm, const float* __restrict__ Im,
    const float* __restrict__ Jm, const float* __restrict__ Km,
    ushort* __restrict__ ws)
{
  const int slot = blockIdx.x * 256 + (int)threadIdx.x;  // 0..32767
  const int lane = slot & 63;
  const int kb = (slot >> 6) & 7;
  const int cb = (slot >> 9) & 15;
  const int si = slot >> 13;
  const float* S = (si == 0) ? Rm : (si == 1) ? Im : (si == 2) ? Jm : Km;
  const float* p = S + (cb * 16 + (lane & 15)) * 256 + kb * 32 + (lane >> 4) * 8;
  f32x4 lo = *(const f32x4*)p;
  f32x4 hi = *(const f32x4*)(p + 4);
  u32x4 v;
  v[0] = pk2(lo[0], lo[1]); v[1] = pk2(lo[2], lo[3]);
  v[2] = pk2(hi[0], hi[1]); v[3] = pk2(hi[2], hi[3]);
  *(u32x4*)(ws + (size_t)slot * 8) = v;
  u32x4 n;
  n[0] = v[0] ^ 0x80008000u; n[1] = v[1] ^ 0x80008000u;
  n[2] = v[2] ^ 0x80008000u; n[3] = v[3] ^ 0x80008000u;
  *(u32x4*)(ws + 262144 + (size_t)slot * 8) = n;  // negated copy at +512 KB
}

// ===========================================================================
// Pass 2 (gemm10): block 128x128, 4 waves 2x2 (wave 64x64, acc=64 AGPR).
// ZERO BARRIERS. Each wave stages its OWN 4 A-frags (private LDS region,
// 3 bufs) via global_load_lds; gload_lds->ds_read ordered by the same-wave
// vmcnt(8) (vmcnt retirement = LDS write complete). B frag-direct from the
// PRE-SIGNED wsb (sign = base-pointer select; no XOR, no branch). Steady
// state: 16 vmem in flight, wait vmcnt(8) per slab (T4: never drains).
// LDS WAR: buf[(s+2)%3] last read by this wave at slab s-1 (program order).
// ===========================================================================
#define STAGE10(s, lb) do {                                                   \
    _Pragma("unroll")                                                         \
    for (int j = 0; j < 4; ++j) {                                             \
      const ushort* s_ = WSX + ((size_t)(fmA + j) * 32 + (s)) * 512           \
                         + lane * 8;                                          \
      __builtin_amdgcn_global_load_lds((const uint*)s_,                       \
                                       (uint*)((lb) + j * 512), 16, 0, 0);    \
    }                                                                         \
  } while (0)

#define LOADB10(s, BF) do {                                                   \
    const int bsel_ = (s) >> 3;                                               \
    const int si_ = a_idx ^ bsel_;                                            \
    const uint neg_ = (0x284Eu >> ((a_idx << 2) | bsel_)) & 1u;               \
    const ushort* base_ = WSB + (neg_ ? 262144 : 0);                          \
    const int kbq_ = (s) & 7;                                                 \
    _Pragma("unroll")                                                         \
    for (int ni = 0; ni < 4; ++ni)                                            \
      BF[ni] = *(const bf16x8*)(                                              \
          base_ + ((size_t)((si_ * 16 + cb0 + ni) * 8 + kbq_)) * 512          \
          + lane * 8);                                                        \
  } while (0)

#define COMPUTE10(lb, BF) do {                                                \
    _Pragma("unroll")                                                         \
    for (int mi = 0; mi < 4; ++mi) {                                          \
      bf16x8 af_ = *(const bf16x8*)((lb) + mi * 512 + lane * 8);              \
      _Pragma("unroll")                                                       \
      for (int ni = 0; ni < 4; ++ni)                                          \
        acc[mi][ni] = __builtin_amdgcn_mfma_f32_16x16x32_bf16(                \
            af_, BF[ni], acc[mi][ni], 0, 0, 0);                               \
    }                                                                         \
  } while (0)

__global__ __launch_bounds__(256, 3) void qlin_gemm10(
    const ushort* __restrict__ WSX, const ushort* __restrict__ WSB,
    const float* __restrict__ bias, float* __restrict__ Y)
{
  // 2048 blocks = 256 m x 8 n; XCD-bijective swizzle (2048%8==0), n fastest.
  const int per = 2048 >> 3;  // 256
  const int bid = (int)blockIdx.x;
  const int swz = (bid & 7) * per + (bid >> 3);
  const int mblk = swz >> 3;       // 0..255
  const int nblk = swz & 7;        // 0..7
  const int m0 = mblk << 7;
  const int n0 = nblk << 7;
  const int a_idx = nblk >> 1;     // 256-col source quadrant

  const int tid = (int)threadIdx.x;
  const int lane = tid & 63;
  const int wv = tid >> 6;         // 0..3
  const int wr = wv >> 1;          // wave row 0/1
  const int wc = wv & 1;           // wave col 0/1
  const int fmA = (mblk << 3) + (wr << 2);        // this wave's 4 A row-frags
  const int cb0 = ((nblk & 1) << 3) + (wc << 2);  // B col-frag base

  // Private per-wave LDS: [wave][3 bufs][4 frags][512 ushorts] = 48 KB.
  __shared__ __align__(16) ushort smA[4 * 3 * 4 * 512];
  ushort* const myL = smA + wv * (3 * 4 * 512);
  ushort* const lbuf0 = myL;
  ushort* const lbuf1 = myL + 4 * 512;
  ushort* const lbuf2 = myL + 8 * 512;

  bf16x8 bq0[4], bq1[4], bq2[4];
  f32x4 acc[4][4];
#pragma unroll
  for (int i = 0; i < 4; ++i)
#pragma unroll
    for (int j = 0; j < 4; ++j) acc[i][j] = (f32x4)(0.0f);

  // prologue: slabs 0,1 in flight (16 vmem outstanding per wave)
  STAGE10(0, lbuf0); LOADB10(0, bq0);
  STAGE10(1, lbuf1); LOADB10(1, bq1);

  // steady state: 10 iters x 3 slabs; per-wave wait vmcnt(8); no barriers.
#pragma unroll 1
  for (int s = 0; s < 30; s += 3) {
    WAITV8();                                    // slab s landed
    STAGE10(s + 2, lbuf2); LOADB10(s + 2, bq2);  // buf2 last read at slab s-1
    COMPUTE10(lbuf0, bq0);
    WAITV8();
    STAGE10(s + 3, lbuf0); LOADB10(s + 3, bq0);
    COMPUTE10(lbuf1, bq1);
    WAITV8();
    STAGE10(s + 4, lbuf1); LOADB10(s + 4, bq1);
    COMPUTE10(lbuf2, bq2);
  }
  // tail: slab 30 (buf0/bq0), slab 31 (buf1/bq1) — staged by the last iter.
  WAITV8();
  COMPUTE10(lbuf0, bq0);
  WAITV0();
  COMPUTE10(lbuf1, bq1);

  // epilogue: C/D layout col = lane&15, row = (lane>>4)*4 + reg  [m89-verified]
#pragma unroll
  for (int ni = 0; ni < 4; ++ni) {
    const int col = n0 + (wc << 6) + (ni << 4) + (lane & 15);
    const float bv = bias[col];
#pragma unroll
    for (int mi = 0; mi < 4; ++mi) {
      const int r0e = m0 + (wr << 6) + (mi << 4) + ((lane >> 4) << 2);
#pragma unroll
      for (int j = 0; j < 4; ++j)
        Y[(size_t)(r0e + j) * N_TOTAL + col] = acc[mi][ni][j] + bv;
    }
  }
}

// ===========================================================================
// Mid-tier: 256x256 tile, B frag-direct (positive half), A LDS. (r7 struct)
// ===========================================================================
#define BM2 256
#define BN2 256
#define BK2 64
#define NT2 512
#define NSTEPS2 (K_TOTAL / BK2)

#define LOAD_A2(kk) do {                                                      \
    _Pragma("unroll")                                                         \
    for (int cc = 0; cc < 4; ++cc) {                                          \
      const float* pa_ = X + (size_t)(m0 + r0 + 64 * cc) * K_TOTAL + (kk) + k0;\
      rA[2 * cc]     = *(const f32x4*)pa_;                                    \
      rA[2 * cc + 1] = *(const f32x4*)(pa_ + 4);                              \
    }                                                                         \
  } while (0)

#define COMMIT_A2(dst) do {                                                   \
    _Pragma("unroll")                                                         \
    for (int cc = 0; cc < 4; ++cc) {                                          \
      u32x4 va_;                                                              \
      va_[0] = pk2(rA[2 * cc][0], rA[2 * cc][1]);                             \
      va_[1] = pk2(rA[2 * cc][2], rA[2 * cc][3]);                             \
      va_[2] = pk2(rA[2 * cc + 1][0], rA[2 * cc + 1][1]);                     \
      va_[3] = pk2(rA[2 * cc + 1][2], rA[2 * cc + 1][3]);                     \
      *(u32x4*)((dst) + sbase + 8192 * cc) = va_;                             \
    }                                                                         \
  } while (0)

#define LOAD_B2(kk) do {                                                      \
    const int bsel_ = (kk) >> 8;                                              \
    const int si_ = a_idx ^ bsel_;                                            \
    const int kbq_ = ((kk) & 255) >> 5;                                       \
    const ushort* fb_ = WS + ((size_t)((si_ * 16 + wc4) * 8 + kbq_)) * 512    \
                        + lane * 8;                                           \
    _Pragma("unroll")                                                         \
    for (int ks = 0; ks < 2; ++ks)                                            \
      _Pragma("unroll")                                                       \
      for (int ni = 0; ni < 4; ++ni)                                          \
        bq[ks * 4 + ni] = *(const bf16x8*)(fb_ + (ni * 8 + ks) * 512);        \
    if ((0x284Eu >> ((a_idx << 2) | bsel_)) & 1u) {                           \
      _Pragma("unroll")                                                       \
      for (int f = 0; f < 8; ++f) {                                           \
        u32x4 u_ = __builtin_bit_cast(u32x4, bq[f]);                          \
        u_[0] ^= 0x80008000u; u_[1] ^= 0x80008000u;                           \
        u_[2] ^= 0x80008000u; u_[3] ^= 0x80008000u;                           \
        bq[f] = __builtin_bit_cast(bf16x8, u_);                               \
      }                                                                       \
    }                                                                         \
  } while (0)

#define COMPUTE2(src) do {                                                    \
    _Pragma("unroll")                                                         \
    for (int ks = 0; ks < 2; ++ks) {                                          \
      _Pragma("unroll")                                                       \
      for (int mi = 0; mi < 8; ++mi) {                                        \
        const int row_ = frow_a0 + (mi << 4);                                 \
        const int kb_ = (ks << 6) + fkb;                                      \
        bf16x8 af_ = *(const bf16x8*)((src) + row_ * (BK2 * 2)                \
                                      + (kb_ ^ ((row_ & 7) << 4)));           \
        _Pragma("unroll")                                                     \
        for (int ni = 0; ni < 4; ++ni)                                        \
          acc[mi][ni] = __builtin_amdgcn_mfma_f32_16x16x32_bf16(              \
              af_, bq[ks * 4 + ni], acc[mi][ni], 0, 0, 0);                    \
      }                                                                       \
    }                                                                         \
  } while (0)

__global__ __launch_bounds__(NT2, 2) void qlin_gemm2(
    const float* __restrict__ X, const ushort* __restrict__ WS,
    const float* __restrict__ bias, float* __restrict__ Y)
{
  const int per = ((M_TOTAL / BM2) * (N_TOTAL / BN2)) >> 3;  // 64
  const int bid = (int)blockIdx.x;
  const int swz = (bid & 7) * per + (bid >> 3);
  const int m0 = (swz >> 2) * BM2;
  const int nblk = swz & 3;
  const int n0 = nblk * BN2;
  const int a_idx = nblk;

  const int tid = (int)threadIdx.x;
  const int lane = tid & 63;
  const int wave = tid >> 6;
  const int wm = (wave >> 2) << 7;
  const int wc4 = (wave & 3) << 2;

  __shared__ __align__(16) ushort smA[2 * BM2 * BK2];  // 64 KB dbuf
  char* const cS = (char*)smA;

  const int r0 = tid >> 3;
  const int k0 = (tid & 7) << 3;
  const int sbase = r0 * (BK2 * 2) + ((k0 * 2) ^ ((r0 & 7) << 4));

  f32x4 rA[8];
  bf16x8 bq[8];
  f32x4 acc[8][4];
#pragma unroll
  for (int i = 0; i < 8; ++i)
#pragma unroll
    for (int j = 0; j < 4; ++j) acc[i][j] = (f32x4)(0.0f);

  const int frow_a0 = wm + (lane & 15);
  const int fkb = (lane >> 4) << 4;

  LOAD_A2(0);
  COMMIT_A2(cS);
  LOAD_A2(BK2);
  SOFT_BARRIER();

#pragma unroll 1
  for (int k = 0; k < NSTEPS2; ++k) {
    char* const rbuf = cS + ((k & 1) << 15);
    char* const wbuf = cS + (((k + 1) & 1) << 15);
    COMMIT_A2(wbuf);
    LOAD_B2(k * BK2);
    if (k + 2 < NSTEPS2) LOAD_A2((k + 2) * BK2);
    COMPUTE2(rbuf);
    SOFT_BARRIER();
  }

#pragma unroll
  for (int ni = 0; ni < 4; ++ni) {
    const int col = n0 + (wc4 << 4) + (ni << 4) + (lane & 15);
    const float bv = bias[col];
#pragma unroll
    for (int mi = 0; mi < 8; ++mi) {
      const int r0e = m0 + wm + (mi << 4) + ((lane >> 4) << 2);
#pragma unroll
      for (int j = 0; j < 4; ++j)
        Y[(size_t)(r0e + j) * N_TOTAL + col] = acc[mi][ni][j] + bv;
    }
  }
}

// ===========================================================================
// No-ws fallback (round-6, 126 us).
// ===========================================================================
#define BM 128
#define BN 128
#define BK 64
#define NTHREADS 256
#define NSTEPS (K_TOTAL / BK)

#define LOAD_TILE(kk) do {                                                    \
    const int si_ = a_idx ^ ((kk) >> 8);                                      \
    const float* Bsrc_ = (si_ == 0) ? Rm : (si_ == 1) ? Im                    \
                       : (si_ == 2) ? Jm : Km;                                \
    const int kloc_ = (kk) & 255;                                             \
    _Pragma("unroll")                                                         \
    for (int cc = 0; cc < 4; ++cc) {                                          \
      const float* pa_ = X + (size_t)(m0 + r0 + 32 * cc) * K_TOTAL + (kk) + k0;\
      rA[2 * cc]     = *(const f32x4*)pa_;                                    \
      rA[2 * cc + 1] = *(const f32x4*)(pa_ + 4);                              \
      const float* pb_ = Bsrc_ + (o_src + r0 + 32 * cc) * 256 + kloc_ + k0;   \
      rB[2 * cc]     = *(const f32x4*)pb_;                                    \
      rB[2 * cc + 1] = *(const f32x4*)(pb_ + 4);                              \
    }                                                                         \
  } while (0)

#define COMMIT_TILE(kk, dst) do {                                             \
    const uint neg_ = (0x284Eu >> ((a_idx << 2) | ((kk) >> 8))) & 1u;         \
    _Pragma("unroll")                                                         \
    for (int cc = 0; cc < 4; ++cc) {                                          \
      u32x4 va_;                                                              \
      va_[0] = pk2(rA[2 * cc][0], rA[2 * cc][1]);                             \
      va_[1] = pk2(rA[2 * cc][2], rA[2 * cc][3]);                             \
      va_[2] = pk2(rA[2 * cc + 1][0], rA[2 * cc + 1][1]);                     \
      va_[3] = pk2(rA[2 * cc + 1][2], rA[2 * cc + 1][3]);                     \
      *(u32x4*)((dst) + sbase + 4096 * cc) = va_;                             \
    }                                                                         \
    if (neg_) {                                                               \
      _Pragma("unroll")                                                       \
      for (int cc = 0; cc < 4; ++cc) {                                        \
        u32x4 vb_;                                                            \
        vb_[0] = pk2(-rB[2 * cc][0], -rB[2 * cc][1]);                         \
        vb_[1] = pk2(-rB[2 * cc][2], -rB[2 * cc][3]);                         \
        vb_[2] = pk2(-rB[2 * cc + 1][0], -rB[2 * cc + 1][1]);                 \
        vb_[3] = pk2(-rB[2 * cc + 1][2], -rB[2 * cc + 1][3]);                 \
        *(u32x4*)((dst) + 16384 + sbase + 4096 * cc) = vb_;                   \
      }                                                                       \
    } else {                                                                  \
      _Pragma("unroll")                                                       \
      for (int cc = 0; cc < 4; ++cc) {                                        \
        u32x4 vb_;                                                            \
        vb_[0] = pk2(rB[2 * cc][0], rB[2 * cc][1]);                           \
        vb_[1] = pk2(rB[2 * cc][2], rB[2 * cc][3]);                           \
        vb_[2] = pk2(rB[2 * cc + 1][0], rB[2 * cc + 1][1]);                   \
        vb_[3] = pk2(rB[2 * cc + 1][2], rB[2 * cc + 1][3]);                   \
        *(u32x4*)((dst) + 16384 + sbase + 4096 * cc) = vb_;                   \
      }                                                                       \
    }                                                                         \
  } while (0)

#define COMPUTE_TILE(src) do {                                                \
    _Pragma("unroll")                                                         \
    for (int ks = 0; ks < 2; ++ks) {                                          \
      const int kb_ = (ks << 6) + fkb;                                        \
      bf16x8 af_[4], bf_[4];                                                  \
      _Pragma("unroll")                                                       \
      for (int mi = 0; mi < 4; ++mi) {                                        \
        const int row_ = frow_a0 + (mi << 4);                                 \
        af_[mi] = *(const bf16x8*)((src) + row_ * (BK * 2)                    \
                                   + (kb_ ^ ((row_ & 7) << 4)));              \
      }                                                                       \
      _Pragma("unroll")                                                       \
      for (int ni = 0; ni < 4; ++ni) {                                        \
        const int row_ = frow_b0 + (ni << 4);                                 \
        bf_[ni] = *(const bf16x8*)((src) + 16384 + row_ * (BK * 2)            \
                                   + (kb_ ^ ((row_ & 7) << 4)));              \
      }                                                                       \
      _Pragma("unroll")                                                       \
      for (int mi = 0; mi < 4; ++mi)                                          \
        _Pragma("unroll")                                                     \
        for (int ni = 0; ni < 4; ++ni)                                        \
          acc[mi][ni] = __builtin_amdgcn_mfma_f32_16x16x32_bf16(              \
              af_[mi], bf_[ni], acc[mi][ni], 0, 0, 0);                        \
    }                                                                         \
  } while (0)

__global__ __launch_bounds__(NTHREADS, 2) void qlin_gemm(
    const float* __restrict__ X, const float* __restrict__ Rm,
    const float* __restrict__ Im, const float* __restrict__ Jm,
    const float* __restrict__ Km, const float* __restrict__ bias,
    float* __restrict__ Y)
{
  const int per = ((M_TOTAL / BM) * (N_TOTAL / BN)) >> 3;
  const int bid = (int)blockIdx.x;
  const int swz = (bid & 7) * per + (bid >> 3);
  const int m0 = (swz >> 3) * BM;
  const int n0 = (swz & 7) * BN;

  const int tid = (int)threadIdx.x;
  const int lane = tid & 63;
  const int wave = tid >> 6;
  const int wm = (wave >> 1) << 6;
  const int wn = (wave & 1) << 6;

  __shared__ __align__(16) ushort sm[2 * 2 * BM * BK];
  char* const cS = (char*)sm;

  const int a_idx = n0 >> 8;
  const int o_src = n0 & 255;

  const int r0 = tid >> 3;
  const int k0 = (tid & 7) << 3;
  const int sbase = r0 * (BK * 2) + ((k0 * 2) ^ ((r0 & 7) << 4));

  f32x4 rA[8], rB[8];
  f32x4 acc[4][4];
#pragma unroll
  for (int i = 0; i < 4; ++i)
#pragma unroll
    for (int j = 0; j < 4; ++j) acc[i][j] = (f32x4)(0.0f);

  const int frow_a0 = wm + (lane & 15);
  const int frow_b0 = wn + (lane & 15);
  const int fkb = (lane >> 4) << 4;

  LOAD_TILE(0);
  COMMIT_TILE(0, cS);
  LOAD_TILE(BK);
  SOFT_BARRIER();

#pragma unroll 1
  for (int k = 0; k < NSTEPS; ++k) {
    char* const rbuf = cS + ((k & 1) << 15);
    char* const wbuf = cS + (((k + 1) & 1) << 15);
    if (k + 1 < NSTEPS) COMMIT_TILE((k + 1) * BK, wbuf);
    if (k + 2 < NSTEPS) LOAD_TILE((k + 2) * BK);
    COMPUTE_TILE(rbuf);
    SOFT_BARRIER();
  }

#pragma unroll
  for (int ni = 0; ni < 4; ++ni) {
    const int col = n0 + wn + (ni << 4) + (lane & 15);
    const float bv = bias[col];
#pragma unroll
    for (int mi = 0; mi < 4; ++mi) {
      const int r0e = m0 + wm + (mi << 4) + ((lane >> 4) << 2);
#pragma unroll
      for (int j = 0; j < 4; ++j)
        Y[(size_t)(r0e + j) * N_TOTAL + col] = acc[mi][ni][j] + bv;
    }
  }
}

extern "C" void kernel_launch(void* const* d_in, const int* in_sizes, int n_in,
                              void* d_out, int out_size, void* d_ws, size_t ws_size,
                              hipStream_t stream) {
  const float* X = (const float*)d_in[0];
  const float* Rm = (const float*)d_in[1];
  const float* Im = (const float*)d_in[2];
  const float* Jm = (const float*)d_in[3];
  const float* Km = (const float*)d_in[4];
  const float* bias = (const float*)d_in[5];
  float* Y = (float*)d_out;

  const size_t needB = (size_t)4 * 256 * 256 * 2;            // 512 KB
  const size_t needB2 = 2 * needB;                           // 1 MB pre-signed
  const size_t needX = (size_t)M_TOTAL * K_TOTAL * 2;        // 64 MB

  if (ws_size >= needX + needB2) {
    ushort* wsx = (ushort*)d_ws;
    ushort* wsb = wsx + (size_t)M_TOTAL * K_TOTAL;
    conv_x<<<dim3(16384), dim3(256), 0, stream>>>(X, wsx);
    conv_b2<<<dim3(128), dim3(256), 0, stream>>>(Rm, Im, Jm, Km, wsb);
    qlin_gemm10<<<dim3(2048), dim3(256), 0, stream>>>(wsx, wsb, bias, Y);
  } else if (ws_size >= needB) {
    ushort* wsb = (ushort*)d_ws;
    // conv_b2 writes positive half first; gemm2 uses only the positive half.
    if (ws_size >= needB2) {
      conv_b2<<<dim3(128), dim3(256), 0, stream>>>(Rm, Im, Jm, Km, wsb);
    } else {
      conv_b2<<<dim3(128), dim3(256), 0, stream>>>(Rm, Im, Jm, Km, wsb);
    }
    qlin_gemm2<<<dim3((M_TOTAL / BM2) * (N_TOTAL / BN2)), dim3(NT2), 0, stream>>>(
        X, wsb, bias, Y);
  } else {
    qlin_gemm<<<dim3((M_TOTAL / BM) * (N_TOTAL / BN)), dim3(NTHREADS), 0, stream>>>(
        X, Rm, Im, Jm, Km, bias, Y);
  }
}